// Round 1
// 99.824 us; speedup vs baseline: 1.0030x; 1.0030x over previous
//
#include <hip/hip_runtime.h>
#include <math.h>

#define BATCH 8
#define TLEN 2000
#define DIM 512
#define MLEN (TLEN + 1)
#define NTH 1024             // scan block size
#define KMAX 1000            // fires are >=2 apart, first at t>=1  =>  K <= 1000 always

// K1: weight[b,t] = sigmoid(dot(feat[b,t,:], W) + bias). One wave per row.
__global__ __launch_bounds__(256) void weight_kernel(
    const float* __restrict__ feat, const float* __restrict__ W,
    const float* __restrict__ bias, float* __restrict__ weight) {
  int gwave = (blockIdx.x * 256 + threadIdx.x) >> 6;   // global wave id = row
  int lane  = threadIdx.x & 63;
  if (gwave >= BATCH * TLEN) return;
  const float4* f4 = (const float4*)feat + (size_t)gwave * (DIM / 4) + lane * 2;
  const float4* w4 = (const float4*)W + lane * 2;
  float4 a0 = f4[0], a1 = f4[1];
  float4 b0 = w4[0], b1 = w4[1];
  float s = a0.x * b0.x + a0.y * b0.y + a0.z * b0.z + a0.w * b0.w +
            a1.x * b1.x + a1.y * b1.y + a1.z * b1.z + a1.w * b1.w;
#pragma unroll
  for (int off = 32; off > 0; off >>= 1) s += __shfl_xor(s, off, 64);
  if (lane == 0) {
    float x = s + bias[0];
    weight[gwave] = 1.0f / (1.0f + expf(-x));
  }
}

// K2: fully parallel integrate-and-fire. Prefix sum (wave shuffles) ->
// next-fire table G0 (batched binary search) -> orbit via RADIX-4 binary
// lifting (table squared twice per barrier in-register, fire list extended
// x4 per barrier). K <= 1000 provably (fires >= 2 apart), so exactly 5
// levels reach flen=1024 — no early-exit flags, no fire-count phase.
// Barriers: 2 (prefix) + 1 (search) + 5 (lifting) = 8  (was ~16).
__global__ __launch_bounds__(NTH) void scan_kernel(
    const float* __restrict__ weight, float* __restrict__ hlens_out,
    int4* __restrict__ AB) {
  int b = blockIdx.x;
  int tid = threadIdx.x;
  int lane = tid & 63, wid = tid >> 6;

  __shared__ float w_s[TLEN];
  __shared__ float S_s[TLEN];
  __shared__ float wtot[16];
  __shared__ unsigned short Ga_s[MLEN];    // ping
  __shared__ unsigned short Gb_s[MLEN];    // pong
  __shared__ unsigned short F_s[1024];     // fire positions (K <= 1000)

  // --- Phase 1: load + prefix sum via wave shuffles (2 elems/thread) ---
  const float* wrow = weight + b * TLEN;
  int base = tid * 2;
  float w0 = 0.f, w1 = 0.f;
  if (base < TLEN) {
    float2 v = *(const float2*)(wrow + base);
    w0 = v.x; w1 = v.y;
  }
  float mysum = w0 + w1;
  float sc = mysum;
#pragma unroll
  for (int d = 1; d < 64; d <<= 1) {
    float o = __shfl_up(sc, d, 64);
    if (lane >= d) sc += o;
  }
  if (lane == 63) wtot[wid] = sc;
  __syncthreads();
  float woff = 0.f;
  for (int j = 0; j < wid; j++) woff += wtot[j];
  float excl = woff + (sc - mysum);
  if (base < TLEN) {
    w_s[base] = w0; w_s[base + 1] = w1;
    S_s[base] = excl + w0;
    S_s[base + 1] = excl + w0 + w1;
  }
  if (tid == 0) {
    float tot = 0.f;
    for (int j = 0; j < 16; j++) tot += wtot[j];
    hlens_out[b] = ceilf(tot);              // hlens tol ~20: order irrelevant
  }
  __syncthreads();

  // --- Phase 2: G0[s] = min t>s with S[t] > S[s]+1; t0 = min t, S[t] > 1 ---
  // w <= 1 and strict '>' imply no fire within 1 step: search starts at s+2.
  {
    int l0 = (tid + 2 < TLEN) ? tid + 2 : TLEN, r0 = TLEN;
    float tg0 = S_s[tid] + 1.0f;
    int s1v = tid + 1024;
    bool has1 = (s1v < TLEN);
    int l1 = has1 ? ((s1v + 2 < TLEN) ? s1v + 2 : TLEN) : TLEN, r1 = TLEN;
    float tg1 = has1 ? S_s[s1v] + 1.0f : 0.f;
    bool has2 = (tid == 0);
    int l2 = 0, r2 = has2 ? TLEN : 0;
#pragma unroll
    for (int step = 0; step < 11; step++) {
      if (l0 < r0) { int m = (l0 + r0) >> 1; if (S_s[m] > tg0) r0 = m; else l0 = m + 1; }
      if (l1 < r1) { int m = (l1 + r1) >> 1; if (S_s[m] > tg1) r1 = m; else l1 = m + 1; }
      if (l2 < r2) { int m = (l2 + r2) >> 1; if (S_s[m] > 1.0f) r2 = m; else l2 = m + 1; }
    }
    Ga_s[tid] = (unsigned short)l0;
    if (has1) Ga_s[s1v] = (unsigned short)l1;
    if (tid == 0) {
      Ga_s[TLEN] = (unsigned short)TLEN;    // sentinel self-loop
      F_s[0] = (unsigned short)l2;          // first fire (TLEN if none)
    }
  }
  __syncthreads();

  // --- Phase 3: radix-4 lifting, 1 barrier/level, exactly 5 levels ---
  // Level l: cur jumps 4^l fires. Extend F[flen..4*flen) via chained cur
  // reads; square table twice in-register for the next level (skip at l=4).
  {
    unsigned short* cur = Ga_s;
    unsigned short* nxt = Gb_s;
    int flen = 1;
#pragma unroll
    for (int lvl = 0; lvl < 5; lvl++) {
      if (tid < flen) {                      // flen <= 256 here
        int e1 = (int)cur[(int)F_s[tid]];
        int e2 = (int)cur[e1];
        int e3 = (int)cur[e2];
        F_s[flen + tid] = (unsigned short)e1;
        F_s[2 * flen + tid] = (unsigned short)e2;
        F_s[3 * flen + tid] = (unsigned short)e3;
      }
      if (lvl < 4) {
        int a0 = (int)cur[tid];
        a0 = (int)cur[a0]; a0 = (int)cur[a0]; a0 = (int)cur[a0];
        nxt[tid] = (unsigned short)a0;
        int s1v = tid + 1024;
        if (s1v <= TLEN) {
          int a1 = (int)cur[s1v];
          a1 = (int)cur[a1]; a1 = (int)cur[a1]; a1 = (int)cur[a1];
          nxt[s1v] = (unsigned short)a1;
        }
      }
      __syncthreads();
      flen <<= 2;
      unsigned short* t = cur; cur = nxt; nxt = t;
    }
  }

  // --- Phase 4: per-frame descriptors AB[m] = {a, e, cL, cR} ---
  // No explicit K needed: m occupied <=> m==0 or F[m-1] < TLEN (m <= KMAX).
  // Interior t of a frame uses w[t]; t==a (m>0) uses cL; t==e uses cR.
#pragma unroll
  for (int it = 0; it < 2; it++) {
    int m = tid + it * 1024;
    if (m >= MLEN) continue;
    int a, e;
    float cL = 0.f, cR = 0.f;
    if (m == 0) {
      a = 0;
      int f0 = (int)F_s[0];
      if (f0 < TLEN) {
        e = f0;
        cR = 1.0f - ((e > 0) ? S_s[e - 1] : 0.f);  // fire split, acc base 0
      } else {
        e = TLEN - 1;
        cR = w_s[TLEN - 1];                        // no fire: plain weight
      }
    } else if (m <= KMAX && (int)F_s[m - 1] < TLEN) {
      int f1 = (int)F_s[m - 1];
      float Sp0 = (m >= 2) ? S_s[(int)F_s[m - 2]] : 0.f;
      a = f1;
      cL = S_s[f1] - Sp0 - 1.0f;                   // leftover c1 at t=a
      int fm = (int)F_s[m];                        // m <= 1000 < 1024: in bounds
      if (fm < TLEN) {
        e = fm;
        cR = 1.0f - (S_s[e - 1] - S_s[f1]);        // fire split c0 at t=e
      } else {
        e = TLEN - 1;
        cR = w_s[TLEN - 1];                        // trailing partial frame
      }
    } else {
      a = 0x7fffffff; e = -1;                      // empty frame
    }
    int4 pk;
    pk.x = a; pk.y = e;
    pk.z = __float_as_int(cL);
    pk.w = __float_as_int(cR);
    AB[(size_t)b * MLEN + m] = pk;
  }
}

// K3: one WAVE per (b, m) frame; 4 waves (256 threads) per block. Each lane
// covers 8 floats of D=512 (two float4s). Coefficients: t==a (m>0) -> cL,
// t==e -> cR, else w[t] (8 KB/batch row, L1/L2-hot broadcast loads).
__global__ __launch_bounds__(256) void gather_kernel(
    const float* __restrict__ feat, const float* __restrict__ weight,
    const int4* __restrict__ AB, float* __restrict__ out) {
  int bm = (blockIdx.x * 256 + threadIdx.x) >> 6;       // global wave id = frame
  int lane = threadIdx.x & 63;
  if (bm >= BATCH * MLEN) return;
  int b = bm / MLEN, m = bm % MLEN;
  int4 ab = AB[(size_t)bm];
  int a = ab.x, e = ab.y;
  float cL = __int_as_float(ab.z), cR = __int_as_float(ab.w);
  float4 acc0 = {0.f, 0.f, 0.f, 0.f};
  float4 acc1 = {0.f, 0.f, 0.f, 0.f};
  const float4* f4 = (const float4*)feat + (size_t)b * TLEN * (DIM / 4) + lane * 2;
  const float* wrow = weight + b * TLEN;
  for (int t = a; t <= e; t++) {            // empty when frame untouched
    float c = (t == a && m > 0) ? cL : ((t == e) ? cR : wrow[t]);
    const float4* fr = f4 + (size_t)t * (DIM / 4);
    float4 fa = fr[0], fb = fr[1];
    acc0.x += c * fa.x; acc0.y += c * fa.y; acc0.z += c * fa.z; acc0.w += c * fa.w;
    acc1.x += c * fb.x; acc1.y += c * fb.y; acc1.z += c * fb.z; acc1.w += c * fb.w;
  }
  float4* orow = (float4*)out + (size_t)bm * (DIM / 4) + lane * 2;
  orow[0] = acc0;
  orow[1] = acc1;
}

extern "C" void kernel_launch(void* const* d_in, const int* in_sizes, int n_in,
                              void* d_out, int out_size, void* d_ws, size_t ws_size,
                              hipStream_t stream) {
  const float* feat = (const float*)d_in[0];
  // d_in[1] = hlens (unused by the reference computation)
  const float* W    = (const float*)d_in[2];
  const float* bias = (const float*)d_in[3];

  float* out       = (float*)d_out;
  float* feat_new  = out;                                  // B*M*D floats
  float* hlens_out = out + (size_t)BATCH * MLEN * DIM;     // 8 floats (int values)

  char* ws = (char*)d_ws;
  float* weight = (float*)ws;                              // B*T floats   (64000 B)
  int4*  AB     = (int4*)(ws + 64000);                     // B*M int4    (256128 B)

  weight_kernel<<<(BATCH * TLEN) / 4, 256, 0, stream>>>(feat, W, bias, weight);
  scan_kernel<<<BATCH, NTH, 0, stream>>>(weight, hlens_out, AB);
  int nframes = BATCH * MLEN;                              // one wave each
  gather_kernel<<<(nframes + 3) / 4, 256, 0, stream>>>(feat, weight, AB, feat_new);
}